// Round 1
// baseline (585.838 us; speedup 1.0000x reference)
//
#include <hip/hip_runtime.h>
#include <cstdint>
#include <cstddef>

// ---------------------------------------------------------------------------
// RawRoutedMoA: B=256, T=512, D=512, HIDDEN=64, DOUT=128, K=5 experts, top-2.
// Plan:
//   k_prep   : pack cv_conv_w (64,512,8) fp32 -> bf16 MFMA B-fragment order
//   k_router : raw_input conv16/stride16 -> gelu -> pool -> head -> top2 gates
//   k_main   : per-b fused pass over h: mean/max pools, online-softmax attn
//              pool, and cv-conv as bf16 MFMA GEMM (M=16 p's per 68-row LDS
//              window, N=64 o, K=4096), gelu + p-mean -> zmean
//   k_epi    : 4x MLP(512->64 gelu ->128) + cv head + gated combine -> out
// ---------------------------------------------------------------------------

using short8   = short   __attribute__((ext_vector_type(8)));
using ushort4v = unsigned short __attribute__((ext_vector_type(4)));
using f32x4    = float   __attribute__((ext_vector_type(4)));

__device__ __forceinline__ unsigned short f2bf(float f) {
  unsigned int u = __float_as_uint(f);
  u += 0x7FFFu + ((u >> 16) & 1u);          // RNE to bf16
  return (unsigned short)(u >> 16);
}
__device__ __forceinline__ float bf2f(unsigned short s) {
  return __uint_as_float((unsigned int)s << 16);
}
__device__ __forceinline__ float geluf(float x) {
  return 0.5f * x * (1.0f + erff(x * 0.7071067811865475f));
}

// ---------------------------------------------------------------------------
// k_prep: prepackB[flat], flat = ((ot*128 + s)*64 + lane)*8 + j
//   o = ot*16 + (lane&15); k = s>>4; c = (s&15)*32 + (lane>>4)*8 + j
//   value = cv_conv_w[o][c][k]
// ---------------------------------------------------------------------------
__global__ __launch_bounds__(256) void k_prep(const float* __restrict__ wcv,
                                              unsigned short* __restrict__ pB) {
  int flat = blockIdx.x * 256 + threadIdx.x;      // < 262144
  int jj   = flat & 7;
  int lane = (flat >> 3) & 63;
  int s    = (flat >> 9) & 127;
  int ot   = flat >> 16;
  int o = ot * 16 + (lane & 15);
  int k = s >> 4;
  int c = ((s & 15) << 5) + ((lane >> 4) << 3) + jj;
  pB[flat] = f2bf(wcv[(o * 512 + c) * 8 + k]);
}

// ---------------------------------------------------------------------------
// k_router: one block (64 thr) per batch element
// ---------------------------------------------------------------------------
__global__ __launch_bounds__(64) void k_router(
    const float* __restrict__ raw, const float* __restrict__ wc,
    const float* __restrict__ bc, const float* __restrict__ wh,
    const float* __restrict__ bh, float* __restrict__ gates) {
  __shared__ float xr[512];
  __shared__ float gbuf[512];
  __shared__ float f2[64];
  __shared__ float lg[5];
  int b = blockIdx.x, tid = threadIdx.x;
#pragma unroll
  for (int i = 0; i < 8; ++i) xr[tid + 64 * i] = raw[b * 512 + tid + 64 * i];
  __syncthreads();
  for (int u = 0; u < 8; ++u) {
    int oi = tid + 64 * u;
    int jf = oi >> 5, tp = oi & 31;
    float s = bc[jf];
    int base = 16 * tp - 8;                        // stride 16, pad 8
#pragma unroll
    for (int k = 0; k < 32; ++k) {
      int ix = base + k;
      if (ix >= 0 && ix < 512) s += xr[ix] * wc[jf * 32 + k];
    }
    gbuf[oi] = geluf(s);
  }
  __syncthreads();
  {
    int base = (tid >> 2) * 32 + (tid & 3) * 8;    // (16,4,8).mean(-1)
    float acc = 0.0f;
#pragma unroll
    for (int u = 0; u < 8; ++u) acc += gbuf[base + u];
    f2[tid] = acc * 0.125f;
  }
  __syncthreads();
  if (tid < 5) {
    float s = bh[tid];
    for (int i = 0; i < 64; ++i) s += f2[i] * wh[i * 5 + tid];
    lg[tid] = s;
  }
  __syncthreads();
  if (tid == 0) {
    float v[5];
#pragma unroll
    for (int e = 0; e < 5; ++e) v[e] = lg[e];
    int i0 = 0;
    for (int e = 1; e < 5; ++e) if (v[e] > v[i0]) i0 = e;   // first max
    int i1 = -1;
    for (int e = 0; e < 5; ++e)
      if (e != i0 && (i1 < 0 || v[e] > v[i1])) i1 = e;      // second
    float e1 = __expf(v[i1] - v[i0]);
    float w0 = 1.0f / (1.0f + e1);
    float g[5] = {0, 0, 0, 0, 0};
    g[i0] = w0; g[i1] = 1.0f - w0;
    for (int e = 0; e < 5; ++e) gates[b * 5 + e] = g[e];
  }
}

// ---------------------------------------------------------------------------
// k_main: one WG (512 thr, 8 waves) per batch element.
// LDS: 2 x 68-row bf16 window (69632 B each) + zscr(8KB) + sc/part
// Window j covers t in [64j-2, 64j+66); p-block j = [16j, 16j+16).
// Swizzle: byteoff ^= ((byteoff>>12)&7)<<4  (rows stride 4 in A-frags)
// ---------------------------------------------------------------------------
#define BUF_BYTES 69632
#define ZSCR_OFF  (2 * BUF_BYTES)           // 139264
#define SC_OFF    (ZSCR_OFF + 2048 * 4)     // 147456
#define PART_OFF  (SC_OFF + 68 * 4)         // 147728
#define SMEM_MAIN (PART_OFF + 136 * 4)      // 148272

__global__ __launch_bounds__(512, 2) void k_main(
    const float* __restrict__ h, const float* __restrict__ apw,
    const float* __restrict__ apb, const unsigned short* __restrict__ pB,
    const float* __restrict__ cvb, float* __restrict__ wsmean,
    float* __restrict__ wsmax, float* __restrict__ wsattn,
    float* __restrict__ wszm) {
  extern __shared__ char smem[];
  float* zscr = (float*)(smem + ZSCR_OFF);
  float* sc   = (float*)(smem + SC_OFF);
  float* part = (float*)(smem + PART_OFF);

  const int tid  = threadIdx.x;
  const int lane = tid & 63;
  const int wave = tid >> 6;
  const int b    = blockIdx.x;
  const float* hb = h + (size_t)b * 512 * 512;
  const int c4  = (tid & 127) << 2;   // this thread's 4 fixed channels
  const int myq = tid >> 7;           // row-parity group (0..3)

  float4 aw = *(const float4*)(apw + c4);
  const float apb0 = apb[0];
  float cvbv = (tid < 64) ? cvb[tid] : 0.0f;

  float s0 = 0, s1 = 0, s2 = 0, s3 = 0;                       // mean partials
  float m0 = -3e38f, m1 = -3e38f, m2 = -3e38f, m3 = -3e38f;   // max partials
  float o0 = 0, o1 = 0, o2 = 0, o3 = 0;                       // attn partials
  float l_run = 0.0f, m_run = -1e30f;                         // online softmax
  float zacc = 0.0f;                                          // gelu(z) p-sum

  auto stage_pool = [&](char* buf, float4 v, int tl) {
    int off = (tl << 10) + (c4 << 1);
    off ^= (off >> 8) & 0x70;
    ushort4v uv;
    uv[0] = f2bf(v.x); uv[1] = f2bf(v.y); uv[2] = f2bf(v.z); uv[3] = f2bf(v.w);
    *(ushort4v*)(buf + off) = uv;
    if (tl >= 2 && tl < 66) {          // wave-uniform predicate
      s0 += v.x; s1 += v.y; s2 += v.z; s3 += v.w;
      m0 = fmaxf(m0, v.x); m1 = fmaxf(m1, v.y);
      m2 = fmaxf(m2, v.z); m3 = fmaxf(m3, v.w);
      float sp = v.x * aw.x + v.y * aw.y + v.z * aw.z + v.w * aw.w;
#pragma unroll
      for (int d = 1; d < 64; d <<= 1) sp += __shfl_xor(sp, d);
      if (lane == 0) part[tl * 2 + (wave & 1)] = sp;
    }
  };

  auto softmax_upd = [&](const char* buf) {
    float cmax = -1e30f;
    for (int r = 0; r < 64; ++r) cmax = fmaxf(cmax, sc[r + 2]);
    float mn = fmaxf(m_run, cmax);
    float scl = __expf(m_run - mn);
    o0 *= scl; o1 *= scl; o2 *= scl; o3 *= scl;
    l_run *= scl; m_run = mn;
#pragma unroll 4
    for (int r = 0; r < 64; ++r) {
      float e = __expf(sc[r + 2] - mn);
      l_run += e;
      if ((r & 3) == myq) {
        int off = ((r + 2) << 10) + (c4 << 1);
        off ^= (off >> 8) & 0x70;
        ushort4v hv = *(const ushort4v*)(buf + off);
        o0 += e * bf2f(hv[0]); o1 += e * bf2f(hv[1]);
        o2 += e * bf2f(hv[2]); o3 += e * bf2f(hv[3]);
      }
    }
  };

  auto conv_block = [&](const char* buf) {
    f32x4 acc = {0.0f, 0.0f, 0.0f, 0.0f};
    const int ot = wave & 3, kh = wave >> 2;
    const int pl = lane & 15, gg = lane >> 4;
#pragma unroll 4
    for (int si = 0; si < 64; ++si) {
      int s = kh * 64 + si;
      int k = s >> 4;
      int c0 = ((s & 15) << 5) + (gg << 3);
      int aoff = ((4 * pl + k) << 10) + (c0 << 1);
      aoff ^= (aoff >> 8) & 0x70;
      short8 av = *(const short8*)(buf + aoff);
      short8 bv = *(const short8*)(pB + ((size_t)((ot * 128 + s) * 64 + lane) << 3));
      acc = __builtin_amdgcn_mfma_f32_16x16x32_bf16(av, bv, acc, 0, 0, 0);
    }
    float* zs = zscr + kh * 1024;
#pragma unroll
    for (int r = 0; r < 4; ++r)
      zs[(gg * 4 + r) * 64 + ot * 16 + pl] = acc[r];   // z[p_local][o]
  };

  // ---- prologue: stage window 0 (rows -2..65, zeros below 0)
  {
#pragma unroll
    for (int i = 0; i < 17; ++i) {
      int f = tid + 512 * i;
      int tl = f >> 7;
      int t = tl - 2;
      float4 v = make_float4(0.f, 0.f, 0.f, 0.f);
      if (t >= 0) v = *(const float4*)(hb + (size_t)t * 512 + c4);
      stage_pool(smem, v, tl);
    }
  }
  __syncthreads();
  if (tid < 64) sc[tid + 2] = part[(tid + 2) * 2] + part[(tid + 2) * 2 + 1] + apb0;
  __syncthreads();
  softmax_upd(smem);

  for (int j = 0; j < 8; ++j) {
    char* cur = smem + (j & 1) * BUF_BYTES;
    char* nxt = smem + ((j + 1) & 1) * BUF_BYTES;
    float4 pf[17];
    if (j < 7) {                       // issue next-window loads early
#pragma unroll
      for (int i = 0; i < 17; ++i) {
        int f = tid + 512 * i;
        int tl = f >> 7;
        int t = 64 * (j + 1) - 2 + tl;
        pf[i] = make_float4(0.f, 0.f, 0.f, 0.f);
        if (t < 512) pf[i] = *(const float4*)(hb + (size_t)t * 512 + c4);
      }
    }
    conv_block(cur);                   // MFMA hides the loads above
    __syncthreads();
    if (tid < 64) {                    // z epilogue: +bias, gelu, p-sum
#pragma unroll 4
      for (int p = 0; p < 16; ++p) {
        float z = zscr[p * 64 + tid] + zscr[1024 + p * 64 + tid] + cvbv;
        zacc += geluf(z);
      }
    }
    __syncthreads();
    if (j < 7) {                       // convert+write+pool next window
#pragma unroll
      for (int i = 0; i < 17; ++i) {
        int f = tid + 512 * i;
        int tl = f >> 7;
        stage_pool(nxt, pf[i], tl);
      }
      __syncthreads();
      if (tid < 64) sc[tid + 2] = part[(tid + 2) * 2] + part[(tid + 2) * 2 + 1] + apb0;
      __syncthreads();
      softmax_upd(nxt);
    }
  }

  // ---- write zmean
  if (tid < 64) wszm[b * 64 + tid] = zacc * (1.0f / 128.0f);

  // ---- combine 4-way pool partials via zscr scratch (2048 floats)
  float invl = 1.0f / l_run;
  {
    float4 t4; t4.x = s0; t4.y = s1; t4.z = s2; t4.w = s3;
    *(float4*)(zscr + myq * 512 + c4) = t4;
    __syncthreads();
    if (tid < 128) {
      int c = tid << 2;
      float4 a = *(float4*)(zscr + c);
      float4 b4 = *(float4*)(zscr + 512 + c);
      float4 c4v = *(float4*)(zscr + 1024 + c);
      float4 d4 = *(float4*)(zscr + 1536 + c);
      float4 r;
      r.x = (a.x + b4.x + c4v.x + d4.x) * (1.0f / 512.0f);
      r.y = (a.y + b4.y + c4v.y + d4.y) * (1.0f / 512.0f);
      r.z = (a.z + b4.z + c4v.z + d4.z) * (1.0f / 512.0f);
      r.w = (a.w + b4.w + c4v.w + d4.w) * (1.0f / 512.0f);
      *(float4*)(wsmean + (size_t)b * 512 + c) = r;
    }
    __syncthreads();
  }
  {
    float4 t4; t4.x = m0; t4.y = m1; t4.z = m2; t4.w = m3;
    *(float4*)(zscr + myq * 512 + c4) = t4;
    __syncthreads();
    if (tid < 128) {
      int c = tid << 2;
      float4 a = *(float4*)(zscr + c);
      float4 b4 = *(float4*)(zscr + 512 + c);
      float4 c4v = *(float4*)(zscr + 1024 + c);
      float4 d4 = *(float4*)(zscr + 1536 + c);
      float4 r;
      r.x = fmaxf(fmaxf(a.x, b4.x), fmaxf(c4v.x, d4.x));
      r.y = fmaxf(fmaxf(a.y, b4.y), fmaxf(c4v.y, d4.y));
      r.z = fmaxf(fmaxf(a.z, b4.z), fmaxf(c4v.z, d4.z));
      r.w = fmaxf(fmaxf(a.w, b4.w), fmaxf(c4v.w, d4.w));
      *(float4*)(wsmax + (size_t)b * 512 + c) = r;
    }
    __syncthreads();
  }
  {
    float4 t4; t4.x = o0; t4.y = o1; t4.z = o2; t4.w = o3;
    *(float4*)(zscr + myq * 512 + c4) = t4;
    __syncthreads();
    if (tid < 128) {
      int c = tid << 2;
      float4 a = *(float4*)(zscr + c);
      float4 b4 = *(float4*)(zscr + 512 + c);
      float4 c4v = *(float4*)(zscr + 1024 + c);
      float4 d4 = *(float4*)(zscr + 1536 + c);
      float4 r;
      r.x = (a.x + b4.x + c4v.x + d4.x) * invl;
      r.y = (a.y + b4.y + c4v.y + d4.y) * invl;
      r.z = (a.z + b4.z + c4v.z + d4.z) * invl;
      r.w = (a.w + b4.w + c4v.w + d4.w) * invl;
      *(float4*)(wsattn + (size_t)b * 512 + c) = r;
    }
  }
}

// ---------------------------------------------------------------------------
// k_epi: one block (256 thr) per batch element: 4 MLPs + cv head + gating
// ---------------------------------------------------------------------------
__global__ __launch_bounds__(256) void k_epi(
    const float* __restrict__ h, const float* __restrict__ gates,
    const float* __restrict__ wsmean, const float* __restrict__ wsmax,
    const float* __restrict__ wsattn, const float* __restrict__ wszm,
    const float* __restrict__ mpw1, const float* __restrict__ mpb1,
    const float* __restrict__ mpw2, const float* __restrict__ mpb2,
    const float* __restrict__ ltw1, const float* __restrict__ ltb1,
    const float* __restrict__ ltw2, const float* __restrict__ ltb2,
    const float* __restrict__ mxw1, const float* __restrict__ mxb1,
    const float* __restrict__ mxw2, const float* __restrict__ mxb2,
    const float* __restrict__ apw1, const float* __restrict__ apb1,
    const float* __restrict__ apw2, const float* __restrict__ apb2,
    const float* __restrict__ cvow, const float* __restrict__ cvob,
    float* __restrict__ out) {
  __shared__ float xs[512];
  __shared__ float hp[256];
  __shared__ float h1[64];
  int b = blockIdx.x, tid = threadIdx.x;
  const int jj = tid & 63, qq = tid >> 6;
  float oacc = 0.0f;
#pragma unroll
  for (int br = 0; br < 4; ++br) {
    const float *w1, *b1, *w2, *b2, *xsrc;
    if (br == 0)      { w1 = mpw1; b1 = mpb1; w2 = mpw2; b2 = mpb2; xsrc = wsmean + (size_t)b * 512; }
    else if (br == 1) { w1 = ltw1; b1 = ltb1; w2 = ltw2; b2 = ltb2; xsrc = h + ((size_t)b * 512 + 511) * 512; }
    else if (br == 2) { w1 = mxw1; b1 = mxb1; w2 = mxw2; b2 = mxb2; xsrc = wsmax + (size_t)b * 512; }
    else              { w1 = apw1; b1 = apb1; w2 = apw2; b2 = apb2; xsrc = wsattn + (size_t)b * 512; }
    xs[tid] = xsrc[tid];
    xs[tid + 256] = xsrc[tid + 256];
    __syncthreads();
    float p = 0.0f;
    for (int c = qq * 128; c < qq * 128 + 128; ++c) p += xs[c] * w1[c * 64 + jj];
    hp[qq * 64 + jj] = p;
    __syncthreads();
    if (tid < 64)
      h1[tid] = geluf(hp[tid] + hp[64 + tid] + hp[128 + tid] + hp[192 + tid] + b1[tid]);
    __syncthreads();
    if (tid < 128) {
      float o = b2[tid];
      for (int hh = 0; hh < 64; ++hh) o += h1[hh] * w2[hh * 128 + tid];
      oacc += gates[b * 5 + br] * o;
    }
    __syncthreads();
  }
  if (tid < 64) h1[tid] = wszm[b * 64 + tid];
  __syncthreads();
  if (tid < 128) {
    float o = cvob[tid];
    for (int hh = 0; hh < 64; ++hh) o += h1[hh] * cvow[hh * 128 + tid];
    oacc += gates[b * 5 + 4] * o;
    out[b * 128 + tid] = oacc;
  }
}

// ---------------------------------------------------------------------------
extern "C" void kernel_launch(void* const* d_in, const int* in_sizes, int n_in,
                              void* d_out, int out_size, void* d_ws, size_t ws_size,
                              hipStream_t stream) {
  const float* h    = (const float*)d_in[0];
  const float* raw  = (const float*)d_in[1];
  const float* rcw  = (const float*)d_in[2];
  const float* rcb  = (const float*)d_in[3];
  const float* rhw  = (const float*)d_in[4];
  const float* rhb  = (const float*)d_in[5];
  const float* mpw1 = (const float*)d_in[6];
  const float* mpb1 = (const float*)d_in[7];
  const float* mpw2 = (const float*)d_in[8];
  const float* mpb2 = (const float*)d_in[9];
  const float* ltw1 = (const float*)d_in[10];
  const float* ltb1 = (const float*)d_in[11];
  const float* ltw2 = (const float*)d_in[12];
  const float* ltb2 = (const float*)d_in[13];
  const float* mxw1 = (const float*)d_in[14];
  const float* mxb1 = (const float*)d_in[15];
  const float* mxw2 = (const float*)d_in[16];
  const float* mxb2 = (const float*)d_in[17];
  const float* apw  = (const float*)d_in[18];
  const float* apb  = (const float*)d_in[19];
  const float* apw1 = (const float*)d_in[20];
  const float* apb1 = (const float*)d_in[21];
  const float* apw2 = (const float*)d_in[22];
  const float* apb2 = (const float*)d_in[23];
  const float* cvw  = (const float*)d_in[24];
  const float* cvbb = (const float*)d_in[25];
  const float* cvow = (const float*)d_in[26];
  const float* cvob = (const float*)d_in[27];

  char* ws = (char*)d_ws;
  float* gates  = (float*)(ws + 0);           // 1280 f32
  float* wszm   = (float*)(ws + 5120);        // 16384 f32
  float* wsmean = (float*)(ws + 70656);       // 131072 f32
  float* wsmax  = (float*)(ws + 594944);      // 131072 f32
  float* wsattn = (float*)(ws + 1119232);     // 131072 f32
  unsigned short* pB = (unsigned short*)(ws + 1643520);  // 262144 bf16

  hipFuncSetAttribute((const void*)k_main,
                      hipFuncAttributeMaxDynamicSharedMemorySize, SMEM_MAIN);

  k_prep<<<1024, 256, 0, stream>>>(cvw, pB);
  k_router<<<256, 64, 0, stream>>>(raw, rcw, rcb, rhw, rhb, gates);
  k_main<<<256, 512, SMEM_MAIN, stream>>>(h, apw, apb, pB, cvbb,
                                          wsmean, wsmax, wsattn, wszm);
  k_epi<<<256, 256, 0, stream>>>(h, gates, wsmean, wsmax, wsattn, wszm,
                                 mpw1, mpb1, mpw2, mpb2, ltw1, ltb1, ltw2, ltb2,
                                 mxw1, mxb1, mxw2, mxb2, apw1, apb1, apw2, apb2,
                                 cvow, cvob, (float*)d_out);
}

// Round 2
// 547.435 us; speedup vs baseline: 1.0702x; 1.0702x over previous
//
#include <hip/hip_runtime.h>
#include <cstdint>
#include <cstddef>

// ---------------------------------------------------------------------------
// RawRoutedMoA: B=256, T=512, D=512, HIDDEN=64, DOUT=128, K=5 experts, top-2.
//   k_prep   : pack cv_conv_w (64,512,8) fp32 -> bf16 MFMA B-fragment order
//   k_router : raw_input conv16/stride16 -> gelu -> pool -> head -> top2 gates
//   k_main   : 512 blocks = (b, t-half). Per block: 4 windows of 64 rows(+4
//              halo). Single-buffered LDS window, pools+scores during staging,
//              no-max softmax accumulation (scores ~N(0,1), exp safe in fp32),
//              conv as bf16 MFMA GEMM. Partials per half -> ws.
//   k_epi    : merge halves + 4x MLP + cv head + gated combine -> out
// ---------------------------------------------------------------------------

using short8   = short   __attribute__((ext_vector_type(8)));
using ushort4v = unsigned short __attribute__((ext_vector_type(4)));
using f32x4    = float   __attribute__((ext_vector_type(4)));

__device__ __forceinline__ unsigned short f2bf(float f) {
  unsigned int u = __float_as_uint(f);
  u += 0x7FFFu + ((u >> 16) & 1u);          // RNE to bf16
  return (unsigned short)(u >> 16);
}
__device__ __forceinline__ float bf2f(unsigned short s) {
  return __uint_as_float((unsigned int)s << 16);
}
__device__ __forceinline__ float geluf(float x) {
  return 0.5f * x * (1.0f + erff(x * 0.7071067811865475f));
}

// ---------------------------------------------------------------------------
// k_prep: pB[flat], flat = ((ot*128 + s)*64 + lane)*8 + j
//   o = ot*16 + (lane&15); k = s>>4; c = (s&15)*32 + (lane>>4)*8 + j
// ---------------------------------------------------------------------------
__global__ __launch_bounds__(256) void k_prep(const float* __restrict__ wcv,
                                              unsigned short* __restrict__ pB) {
  int flat = blockIdx.x * 256 + threadIdx.x;      // < 262144
  int jj   = flat & 7;
  int lane = (flat >> 3) & 63;
  int s    = (flat >> 9) & 127;
  int ot   = flat >> 16;
  int o = ot * 16 + (lane & 15);
  int k = s >> 4;
  int c = ((s & 15) << 5) + ((lane >> 4) << 3) + jj;
  pB[flat] = f2bf(wcv[(o * 512 + c) * 8 + k]);
}

// ---------------------------------------------------------------------------
// k_router: one block (64 thr) per batch element
// ---------------------------------------------------------------------------
__global__ __launch_bounds__(64) void k_router(
    const float* __restrict__ raw, const float* __restrict__ wc,
    const float* __restrict__ bc, const float* __restrict__ wh,
    const float* __restrict__ bh, float* __restrict__ gates) {
  __shared__ float xr[512];
  __shared__ float gbuf[512];
  __shared__ float f2[64];
  __shared__ float lg[5];
  int b = blockIdx.x, tid = threadIdx.x;
#pragma unroll
  for (int i = 0; i < 8; ++i) xr[tid + 64 * i] = raw[b * 512 + tid + 64 * i];
  __syncthreads();
  for (int u = 0; u < 8; ++u) {
    int oi = tid + 64 * u;
    int jf = oi >> 5, tp = oi & 31;
    float s = bc[jf];
    int base = 16 * tp - 8;                        // stride 16, pad 8
#pragma unroll
    for (int k = 0; k < 32; ++k) {
      int ix = base + k;
      if (ix >= 0 && ix < 512) s += xr[ix] * wc[jf * 32 + k];
    }
    gbuf[oi] = geluf(s);
  }
  __syncthreads();
  {
    int base = (tid >> 2) * 32 + (tid & 3) * 8;    // (16,4,8).mean(-1)
    float acc = 0.0f;
#pragma unroll
    for (int u = 0; u < 8; ++u) acc += gbuf[base + u];
    f2[tid] = acc * 0.125f;
  }
  __syncthreads();
  if (tid < 5) {
    float s = bh[tid];
    for (int i = 0; i < 64; ++i) s += f2[i] * wh[i * 5 + tid];
    lg[tid] = s;
  }
  __syncthreads();
  if (tid == 0) {
    float v[5];
#pragma unroll
    for (int e = 0; e < 5; ++e) v[e] = lg[e];
    int i0 = 0;
    for (int e = 1; e < 5; ++e) if (v[e] > v[i0]) i0 = e;   // first max
    int i1 = -1;
    for (int e = 0; e < 5; ++e)
      if (e != i0 && (i1 < 0 || v[e] > v[i1])) i1 = e;      // second
    float e1 = __expf(v[i1] - v[i0]);
    float w0 = 1.0f / (1.0f + e1);
    float g[5] = {0, 0, 0, 0, 0};
    g[i0] = w0; g[i1] = 1.0f - w0;
    for (int e = 0; e < 5; ++e) gates[b * 5 + e] = g[e];
  }
}

// ---------------------------------------------------------------------------
// k_main: 512 blocks (b = bid>>1, half = bid&1), 512 threads, 80544 B LDS
//   -> 2 blocks/CU for cross-block phase overlap.
// LDS: win[68 rows][1024 B] bf16 | zscr[2048 f] | part[68][9] f | esc[64] | lp[4]
// Swizzle (write & both reads): off ^= ((off>>12)&7)<<4   (row>>2 into 16B slot)
// ---------------------------------------------------------------------------
#define ZSCR_OFF   69632
#define PART_OFF   77824
#define ESC_OFF    80272
#define LPART_OFF  80528
#define SMEM_MAIN  80544

__global__ __launch_bounds__(512, 4) void k_main(
    const float* __restrict__ h, const float* __restrict__ apw,
    const float* __restrict__ apb, const unsigned short* __restrict__ pB,
    const float* __restrict__ cvb,
    float* __restrict__ wsmean, float* __restrict__ wsmax,
    float* __restrict__ wsattn, float* __restrict__ wsl,
    float* __restrict__ wszm) {
  extern __shared__ char smem[];
  float* zscr  = (float*)(smem + ZSCR_OFF);
  float* part  = (float*)(smem + PART_OFF);
  float* esc   = (float*)(smem + ESC_OFF);
  float* lpart = (float*)(smem + LPART_OFF);

  const int tid  = threadIdx.x;
  const int lane = tid & 63;
  const int wave = tid >> 6;
  const int bh   = blockIdx.x;
  const int b    = bh >> 1;
  const int half = bh & 1;
  const float* hb = h + (size_t)b * 262144;
  const int c4   = (tid & 127) << 2;   // this thread's 4 fixed channels
  const int myq  = tid >> 7;           // quarter (0..3)

  const float4 aw = *(const float4*)(apw + c4);
  const float apb0 = apb[0];
  const int zp = tid >> 5;             // p_local for z epilogue
  const int zo = (tid & 31) << 1;
  const float cvb0 = cvb[zo], cvb1 = cvb[zo + 1];

  const int ot = wave & 3, kh = wave >> 2;   // conv wave task
  const int pl = lane & 15, gg = lane >> 4;

  float s0=0.f,s1=0.f,s2=0.f,s3=0.f;                       // mean partials
  float m0=-3e38f,m1=-3e38f,m2=-3e38f,m3=-3e38f;           // max partials
  float o0=0.f,o1=0.f,o2=0.f,o3=0.f;                       // attn numerator
  float lsum = 0.f;                                        // attn denominator
  float zacc0 = 0.f, zacc1 = 0.f;                          // gelu(z) p-sums

  for (int jw = 0; jw < 4; ++jw) {
    const int j = half * 4 + jw;
    const int tbase = 64 * j - 2;
    // ---------------- L: stage rows + pools + score partials ----------------
#pragma unroll
    for (int i = 0; i < 17; ++i) {
      const int tl = (tid >> 7) + 4 * i;       // wave-uniform slot
      const int t  = tbase + tl;
      float4 v = make_float4(0.f, 0.f, 0.f, 0.f);
      if (t >= 0 && t < 512) v = *(const float4*)(hb + (size_t)t * 512 + c4);
      int off = (tl << 10) + ((tid & 127) << 3);
      off ^= ((off >> 12) & 7) << 4;
      ushort4v uv;
      uv[0]=f2bf(v.x); uv[1]=f2bf(v.y); uv[2]=f2bf(v.z); uv[3]=f2bf(v.w);
      *(ushort4v*)(smem + off) = uv;
      if (tl >= 2 && tl < 66) {                // main rows only
        s0+=v.x; s1+=v.y; s2+=v.z; s3+=v.w;
        m0=fmaxf(m0,v.x); m1=fmaxf(m1,v.y); m2=fmaxf(m2,v.z); m3=fmaxf(m3,v.w);
        float sp = v.x*aw.x + v.y*aw.y + v.z*aw.z + v.w*aw.w;
        sp += __shfl_xor(sp, 1); sp += __shfl_xor(sp, 2);
        sp += __shfl_xor(sp, 4); sp += __shfl_xor(sp, 8);
        if ((lane & 15) == 0) part[tl * 9 + ((tid & 127) >> 4)] = sp;
      }
    }
    __syncthreads();
    // ---------------- S: combine score partials -> esc (all threads) --------
    {
      const int rr = tid >> 3, jj = tid & 7;
      float p = part[(rr + 2) * 9 + jj];
      p += __shfl_xor(p, 1); p += __shfl_xor(p, 2); p += __shfl_xor(p, 4);
      if (jj == 0) esc[rr] = __expf(p + apb0);   // no max: scores ~N(0,1)
    }
    // ---------------- C: conv MFMA (A from window, B from pB/L2) ------------
    {
      f32x4 acc = {0.f, 0.f, 0.f, 0.f};
      __builtin_amdgcn_s_setprio(1);
#pragma unroll 8
      for (int si = 0; si < 64; ++si) {
        const int s = kh * 64 + si;
        const int k = s >> 4;
        int aoff = ((4 * pl + k) << 10) + ((s & 15) << 6) + (gg << 4);
        aoff ^= ((aoff >> 12) & 7) << 4;
        short8 av = *(const short8*)(smem + aoff);
        short8 bv = *(const short8*)(pB + ((size_t)((ot * 128 + s) * 64 + lane) << 3));
        acc = __builtin_amdgcn_mfma_f32_16x16x32_bf16(av, bv, acc, 0, 0, 0);
      }
      __builtin_amdgcn_s_setprio(0);
      float* zs = zscr + kh * 1024;
#pragma unroll
      for (int r = 0; r < 4; ++r)
        zs[(gg * 4 + r) * 64 + ot * 16 + pl] = acc[r];   // z[p_local][o]
    }
    __syncthreads();
    // ---------------- E: attn accumulation + z epilogue ---------------------
#pragma unroll 4
    for (int u = 0; u < 16; ++u) {
      const int r = u * 4 + myq;
      const float e = esc[r];
      lsum += e;
      int off = ((r + 2) << 10) + ((tid & 127) << 3);
      off ^= ((off >> 12) & 7) << 4;
      ushort4v hv = *(const ushort4v*)(smem + off);
      o0 += e * bf2f(hv[0]); o1 += e * bf2f(hv[1]);
      o2 += e * bf2f(hv[2]); o3 += e * bf2f(hv[3]);
    }
    {
      float2 za = *(const float2*)(zscr + zp * 64 + zo);
      float2 zb = *(const float2*)(zscr + 1024 + zp * 64 + zo);
      zacc0 += geluf(za.x + zb.x + cvb0);
      zacc1 += geluf(za.y + zb.y + cvb1);
    }
    __syncthreads();
  }

  // ---------------- combine partials across quarters -> per-half ws --------
  float* red = (float*)smem;                 // window LDS reused as scratch
  if ((tid & 127) == 0) lpart[myq] = lsum;
  *(float4*)(red + myq * 512 + c4) = make_float4(s0, s1, s2, s3);
  __syncthreads();
  if (tid < 128) {
    const int c = tid << 2;
    float4 a = *(float4*)(red + c);
    float4 b4 = *(float4*)(red + 512 + c);
    float4 cc = *(float4*)(red + 1024 + c);
    float4 d4 = *(float4*)(red + 1536 + c);
    *(float4*)(wsmean + (size_t)bh * 512 + c) =
        make_float4(a.x+b4.x+cc.x+d4.x, a.y+b4.y+cc.y+d4.y,
                    a.z+b4.z+cc.z+d4.z, a.w+b4.w+cc.w+d4.w);
  }
  if (tid == 0) wsl[bh] = lpart[0] + lpart[1] + lpart[2] + lpart[3];
  __syncthreads();
  *(float4*)(red + myq * 512 + c4) = make_float4(m0, m1, m2, m3);
  __syncthreads();
  if (tid < 128) {
    const int c = tid << 2;
    float4 a = *(float4*)(red + c);
    float4 b4 = *(float4*)(red + 512 + c);
    float4 cc = *(float4*)(red + 1024 + c);
    float4 d4 = *(float4*)(red + 1536 + c);
    *(float4*)(wsmax + (size_t)bh * 512 + c) =
        make_float4(fmaxf(fmaxf(a.x,b4.x), fmaxf(cc.x,d4.x)),
                    fmaxf(fmaxf(a.y,b4.y), fmaxf(cc.y,d4.y)),
                    fmaxf(fmaxf(a.z,b4.z), fmaxf(cc.z,d4.z)),
                    fmaxf(fmaxf(a.w,b4.w), fmaxf(cc.w,d4.w)));
  }
  __syncthreads();
  *(float4*)(red + myq * 512 + c4) = make_float4(o0, o1, o2, o3);
  __syncthreads();
  if (tid < 128) {
    const int c = tid << 2;
    float4 a = *(float4*)(red + c);
    float4 b4 = *(float4*)(red + 512 + c);
    float4 cc = *(float4*)(red + 1024 + c);
    float4 d4 = *(float4*)(red + 1536 + c);
    *(float4*)(wsattn + (size_t)bh * 512 + c) =
        make_float4(a.x+b4.x+cc.x+d4.x, a.y+b4.y+cc.y+d4.y,
                    a.z+b4.z+cc.z+d4.z, a.w+b4.w+cc.w+d4.w);
  }
  __syncthreads();
  *(float2*)(red + zp * 64 + zo) = make_float2(zacc0, zacc1);
  __syncthreads();
  if (tid < 64) {
    float s = 0.f;
#pragma unroll
    for (int p = 0; p < 16; ++p) s += red[p * 64 + tid];
    wszm[bh * 64 + tid] = s;                 // raw gelu-sum over this half's p
  }
}

// ---------------------------------------------------------------------------
// k_epi: one block (256 thr) per batch element: merge halves, 4 MLPs + cv head
// ---------------------------------------------------------------------------
__global__ __launch_bounds__(256) void k_epi(
    const float* __restrict__ h, const float* __restrict__ gates,
    const float* __restrict__ wsmean, const float* __restrict__ wsmax,
    const float* __restrict__ wsattn, const float* __restrict__ wsl,
    const float* __restrict__ wszm,
    const float* __restrict__ mpw1, const float* __restrict__ mpb1,
    const float* __restrict__ mpw2, const float* __restrict__ mpb2,
    const float* __restrict__ ltw1, const float* __restrict__ ltb1,
    const float* __restrict__ ltw2, const float* __restrict__ ltb2,
    const float* __restrict__ mxw1, const float* __restrict__ mxb1,
    const float* __restrict__ mxw2, const float* __restrict__ mxb2,
    const float* __restrict__ apw1, const float* __restrict__ apb1,
    const float* __restrict__ apw2, const float* __restrict__ apb2,
    const float* __restrict__ cvow, const float* __restrict__ cvob,
    float* __restrict__ out) {
  __shared__ float xs[512];
  __shared__ float hp[256];
  __shared__ float h1[64];
  int b = blockIdx.x, tid = threadIdx.x;
  const int jj = tid & 63, qq = tid >> 6;
  const float invL = 1.0f / (wsl[2 * b] + wsl[2 * b + 1]);
  float oacc = 0.0f;
#pragma unroll
  for (int br = 0; br < 4; ++br) {
    const float *w1, *b1, *w2, *b2;
    if (br == 0)      { w1 = mpw1; b1 = mpb1; w2 = mpw2; b2 = mpb2; }
    else if (br == 1) { w1 = ltw1; b1 = ltb1; w2 = ltw2; b2 = ltb2; }
    else if (br == 2) { w1 = mxw1; b1 = mxb1; w2 = mxw2; b2 = mxb2; }
    else              { w1 = apw1; b1 = apb1; w2 = apw2; b2 = apb2; }
#pragma unroll
    for (int u = 0; u < 2; ++u) {
      int idx = tid + 256 * u;
      float v;
      if (br == 0)
        v = (wsmean[(size_t)(2*b)*512+idx] + wsmean[(size_t)(2*b+1)*512+idx]) * (1.0f/512.0f);
      else if (br == 1)
        v = h[((size_t)b * 512 + 511) * 512 + idx];
      else if (br == 2)
        v = fmaxf(wsmax[(size_t)(2*b)*512+idx], wsmax[(size_t)(2*b+1)*512+idx]);
      else
        v = (wsattn[(size_t)(2*b)*512+idx] + wsattn[(size_t)(2*b+1)*512+idx]) * invL;
      xs[idx] = v;
    }
    __syncthreads();
    float p = 0.0f;
    for (int c = qq * 128; c < qq * 128 + 128; ++c) p += xs[c] * w1[c * 64 + jj];
    hp[qq * 64 + jj] = p;
    __syncthreads();
    if (tid < 64)
      h1[tid] = geluf(hp[tid] + hp[64 + tid] + hp[128 + tid] + hp[192 + tid] + b1[tid]);
    __syncthreads();
    if (tid < 128) {
      float o = b2[tid];
      for (int hh = 0; hh < 64; ++hh) o += h1[hh] * w2[hh * 128 + tid];
      oacc += gates[b * 5 + br] * o;
    }
    __syncthreads();
  }
  if (tid < 64)
    h1[tid] = (wszm[(2*b)*64 + tid] + wszm[(2*b+1)*64 + tid]) * (1.0f / 128.0f);
  __syncthreads();
  if (tid < 128) {
    float o = cvob[tid];
    for (int hh = 0; hh < 64; ++hh) o += h1[hh] * cvow[hh * 128 + tid];
    oacc += gates[b * 5 + 4] * o;
    out[b * 128 + tid] = oacc;
  }
}

// ---------------------------------------------------------------------------
extern "C" void kernel_launch(void* const* d_in, const int* in_sizes, int n_in,
                              void* d_out, int out_size, void* d_ws, size_t ws_size,
                              hipStream_t stream) {
  const float* h    = (const float*)d_in[0];
  const float* raw  = (const float*)d_in[1];
  const float* rcw  = (const float*)d_in[2];
  const float* rcb  = (const float*)d_in[3];
  const float* rhw  = (const float*)d_in[4];
  const float* rhb  = (const float*)d_in[5];
  const float* mpw1 = (const float*)d_in[6];
  const float* mpb1 = (const float*)d_in[7];
  const float* mpw2 = (const float*)d_in[8];
  const float* mpb2 = (const float*)d_in[9];
  const float* ltw1 = (const float*)d_in[10];
  const float* ltb1 = (const float*)d_in[11];
  const float* ltw2 = (const float*)d_in[12];
  const float* ltb2 = (const float*)d_in[13];
  const float* mxw1 = (const float*)d_in[14];
  const float* mxb1 = (const float*)d_in[15];
  const float* mxw2 = (const float*)d_in[16];
  const float* mxb2 = (const float*)d_in[17];
  const float* apw  = (const float*)d_in[18];
  const float* apb  = (const float*)d_in[19];
  const float* apw1 = (const float*)d_in[20];
  const float* apb1 = (const float*)d_in[21];
  const float* apw2 = (const float*)d_in[22];
  const float* apb2 = (const float*)d_in[23];
  const float* cvw  = (const float*)d_in[24];
  const float* cvbb = (const float*)d_in[25];
  const float* cvow = (const float*)d_in[26];
  const float* cvob = (const float*)d_in[27];

  char* ws = (char*)d_ws;
  float* gates  = (float*)(ws + 0);              // 1280 f32
  float* wsl    = (float*)(ws + 8192);           // 512 f32
  float* wszm   = (float*)(ws + 16384);          // 256*2*64 f32
  float* wsmean = (float*)(ws + 262144);         // 256*2*512 f32 (1 MB)
  float* wsmax  = (float*)(ws + 1310720);        // 1 MB
  float* wsattn = (float*)(ws + 2359296);        // 1 MB
  unsigned short* pB = (unsigned short*)(ws + 3407872);  // 512 KB

  hipFuncSetAttribute((const void*)k_main,
                      hipFuncAttributeMaxDynamicSharedMemorySize, SMEM_MAIN);

  k_prep<<<1024, 256, 0, stream>>>(cvw, pB);
  k_router<<<256, 64, 0, stream>>>(raw, rcw, rcb, rhw, rhb, gates);
  k_main<<<512, 512, SMEM_MAIN, stream>>>(h, apw, apb, pB, cvbb,
                                          wsmean, wsmax, wsattn, wsl, wszm);
  k_epi<<<256, 256, 0, stream>>>(h, gates, wsmean, wsmax, wsattn, wsl, wszm,
                                 mpw1, mpb1, mpw2, mpb2, ltw1, ltb1, ltw2, ltb2,
                                 mxw1, mxb1, mxw2, mxb2, apw1, apb1, apw2, apb2,
                                 cvow, cvob, (float*)d_out);
}